// Round 3
// baseline (10259.914 us; speedup 1.0000x reference)
//
#include <hip/hip_runtime.h>
#include <hip/hip_bf16.h>

// Problem constants (B=2, P=2048, D=768, H=12, hd=64)
#define B_  2
#define P_  2048
#define D_  768
#define H_  12
#define HD_ 64
#define M_  (B_ * P_)   // 4096
#define N1_ (3 * D_)    // 2304

// ---------------------------------------------------------------------------
// Kernel 1: qkv = x @ W_qkv, scattered into [3][B][H][P][hd] fp32 layout.
// Tiled 64x64, BK=16, 256 threads (16x16), 4x4 per thread.
// ---------------------------------------------------------------------------
__global__ __launch_bounds__(256) void gemm_qkv(const float* __restrict__ x,
                                                const float* __restrict__ w,
                                                float* __restrict__ qkv) {
    __shared__ float As[64][17];   // +1 pad
    __shared__ float Bs[16][64];
    const int tid = threadIdx.x;
    const int tx = tid & 15, ty = tid >> 4;
    const int rowBase = blockIdx.y * 64;
    const int colBase = blockIdx.x * 64;
    float acc[4][4] = {};

    for (int k0 = 0; k0 < D_; k0 += 16) {
#pragma unroll
        for (int i = 0; i < 4; i++) {
            int e  = tid + i * 256;
            int ar = e >> 4, ac = e & 15;
            As[ar][ac] = x[(size_t)(rowBase + ar) * D_ + k0 + ac];
            int br = e >> 6, bc = e & 63;
            Bs[br][bc] = w[(size_t)(k0 + br) * N1_ + colBase + bc];
        }
        __syncthreads();
#pragma unroll
        for (int kk = 0; kk < 16; kk++) {
            float a0 = As[ty * 4 + 0][kk];
            float a1 = As[ty * 4 + 1][kk];
            float a2 = As[ty * 4 + 2][kk];
            float a3 = As[ty * 4 + 3][kk];
            float4 bv = *(const float4*)&Bs[kk][tx * 4];
            acc[0][0] += a0 * bv.x; acc[0][1] += a0 * bv.y; acc[0][2] += a0 * bv.z; acc[0][3] += a0 * bv.w;
            acc[1][0] += a1 * bv.x; acc[1][1] += a1 * bv.y; acc[1][2] += a1 * bv.z; acc[1][3] += a1 * bv.w;
            acc[2][0] += a2 * bv.x; acc[2][1] += a2 * bv.y; acc[2][2] += a2 * bv.z; acc[2][3] += a2 * bv.w;
            acc[3][0] += a3 * bv.x; acc[3][1] += a3 * bv.y; acc[3][2] += a3 * bv.z; acc[3][3] += a3 * bv.w;
        }
        __syncthreads();
    }

    // Scatter: column c -> (comp=c/768, h=(c%768)/64, d=c%64); row r -> (b=r/2048, p=r%2048)
#pragma unroll
    for (int i = 0; i < 4; i++) {
        int r  = rowBase + ty * 4 + i;
        int bb = r >> 11;
        int p  = r & 2047;
#pragma unroll
        for (int j = 0; j < 4; j++) {
            int c    = colBase + tx * 4 + j;
            int comp = c / D_;
            int rem  = c - comp * D_;
            int h    = rem >> 6;
            int d    = rem & 63;
            size_t addr = ((((size_t)comp * B_ + bb) * H_ + h) * P_ + p) * HD_ + d;
            qkv[addr] = acc[i][j];
        }
    }
}

// ---------------------------------------------------------------------------
// Kernel 2: per-head LayerNorm over hd=64 for q and k rows, in place.
// One wave per row; q rows also get * hd^-0.5 = 0.125.
// ---------------------------------------------------------------------------
__global__ __launch_bounds__(256) void ln_qk(float* __restrict__ qkv,
                                             const float* __restrict__ qs, const float* __restrict__ qb,
                                             const float* __restrict__ ks, const float* __restrict__ kb) {
    const int wid  = threadIdx.x >> 6;
    const int lane = threadIdx.x & 63;
    const int row  = blockIdx.x * 4 + wid;                 // 0..98303
    const bool is_q = row < B_ * H_ * P_;                  // < 49152
    const size_t base = (size_t)row * HD_;

    float v = qkv[base + lane];
    float s = v;
#pragma unroll
    for (int o = 32; o > 0; o >>= 1) s += __shfl_xor(s, o, 64);
    float mean = s * (1.0f / 64.0f);
    float d  = v - mean;
    float sq = d * d;
#pragma unroll
    for (int o = 32; o > 0; o >>= 1) sq += __shfl_xor(sq, o, 64);
    float inv = rsqrtf(sq * (1.0f / 64.0f) + 1e-6f);
    float sc  = is_q ? qs[lane] : ks[lane];
    float bi  = is_q ? qb[lane] : kb[lane];
    float r   = d * inv * sc + bi;
    if (is_q) r *= 0.125f;
    qkv[base + lane] = r;
}

// ---------------------------------------------------------------------------
// Kernel 3: attention. One block per (b, h, 4 q-rows). 256 threads.
// Phase A: thread t computes scores for keys {t, t+256, ...} x 4 q rows.
// Softmax per row; probabilities in LDS (4 x 2048 fp32 = 32 KB).
// Phase B: wave g accumulates keys j==g mod 4; lane=output dim (coalesced V).
// Output fp32 into d_out used as scratch (fully rewritten by gemm_out later).
// ---------------------------------------------------------------------------
__global__ __launch_bounds__(256) void attn(const float* __restrict__ qkv,
                                            float* __restrict__ attn_s) {
    const int p0  = blockIdx.x * 4;
    const int bh  = blockIdx.y;            // 0..23
    const int b   = bh / H_, h = bh % H_;
    const int tid = threadIdx.x;

    __shared__ float q_s[4 * 64];
    __shared__ float s_e[4][2048];
    __shared__ float redm[4][4];
    __shared__ float reds[4][4];
    __shared__ float partial[4][4][64];

    const size_t hs = (size_t)P_ * HD_;
    const float* qp = qkv + ((size_t)(0 * B_ + b) * H_ + h) * hs + (size_t)p0 * HD_;
    const float* kp = qkv + ((size_t)(1 * B_ + b) * H_ + h) * hs;
    const float* vp = qkv + ((size_t)(2 * B_ + b) * H_ + h) * hs;

    q_s[tid] = qp[tid];        // 4 contiguous q rows = 256 floats
    __syncthreads();

    float sc[8][4];
#pragma unroll
    for (int jo = 0; jo < 8; jo++) {
        int j = tid + jo * 256;
        const float4* k4 = (const float4*)(kp + (size_t)j * HD_);
        const float4* q4 = (const float4*)q_s;
        float a0 = 0.f, a1 = 0.f, a2 = 0.f, a3 = 0.f;
#pragma unroll
        for (int d4 = 0; d4 < 16; d4++) {
            float4 kv = k4[d4];
            float4 qa = q4[d4], qbv = q4[16 + d4], qc = q4[32 + d4], qd = q4[48 + d4];
            a0 += qa.x * kv.x + qa.y * kv.y + qa.z * kv.z + qa.w * kv.w;
            a1 += qbv.x * kv.x + qbv.y * kv.y + qbv.z * kv.z + qbv.w * kv.w;
            a2 += qc.x * kv.x + qc.y * kv.y + qc.z * kv.z + qc.w * kv.w;
            a3 += qd.x * kv.x + qd.y * kv.y + qd.z * kv.z + qd.w * kv.w;
        }
        sc[jo][0] = a0; sc[jo][1] = a1; sc[jo][2] = a2; sc[jo][3] = a3;
    }

    // per-row max
#pragma unroll
    for (int r = 0; r < 4; r++) {
        float m = -1e30f;
#pragma unroll
        for (int jo = 0; jo < 8; jo++) m = fmaxf(m, sc[jo][r]);
#pragma unroll
        for (int o = 32; o > 0; o >>= 1) m = fmaxf(m, __shfl_xor(m, o, 64));
        if ((tid & 63) == 0) redm[r][tid >> 6] = m;
    }
    __syncthreads();
    float mx[4];
#pragma unroll
    for (int r = 0; r < 4; r++)
        mx[r] = fmaxf(fmaxf(redm[r][0], redm[r][1]), fmaxf(redm[r][2], redm[r][3]));

    float ls[4] = {0.f, 0.f, 0.f, 0.f};
#pragma unroll
    for (int jo = 0; jo < 8; jo++) {
        int j = tid + jo * 256;
#pragma unroll
        for (int r = 0; r < 4; r++) {
            float e = __expf(sc[jo][r] - mx[r]);
            s_e[r][j] = e;
            ls[r] += e;
        }
    }
#pragma unroll
    for (int r = 0; r < 4; r++) {
#pragma unroll
        for (int o = 32; o > 0; o >>= 1) ls[r] += __shfl_xor(ls[r], o, 64);
        if ((tid & 63) == 0) reds[r][tid >> 6] = ls[r];
    }
    __syncthreads();   // also guarantees all s_e writes visible
    float tot[4];
#pragma unroll
    for (int r = 0; r < 4; r++) tot[r] = reds[r][0] + reds[r][1] + reds[r][2] + reds[r][3];

    // Phase B: P @ V
    const int g = tid >> 6, dim = tid & 63;
    float acc[4] = {0.f, 0.f, 0.f, 0.f};
    for (int j = g; j < 2048; j += 4) {
        float vv = vp[(size_t)j * HD_ + dim];
#pragma unroll
        for (int r = 0; r < 4; r++) acc[r] += s_e[r][j] * vv;
    }
#pragma unroll
    for (int r = 0; r < 4; r++) partial[r][g][dim] = acc[r];
    __syncthreads();

    {
        int r  = tid >> 6;
        int d2 = tid & 63;
        float o = (partial[r][0][d2] + partial[r][1][d2] + partial[r][2][d2] + partial[r][3][d2]) / tot[r];
        attn_s[(size_t)(b * P_ + p0 + r) * D_ + h * HD_ + d2] = o;
    }
}

// ---------------------------------------------------------------------------
// Kernel 4: LayerNorm over D=768. Reads d_out scratch, writes ln_buf
// (overlays dead q-region of qkv ws). 1 block per row.
// ---------------------------------------------------------------------------
__global__ __launch_bounds__(256) void ln_o(const float* __restrict__ a,
                                            float* __restrict__ lnb,
                                            const float* __restrict__ osc,
                                            const float* __restrict__ ob) {
    __shared__ float red[4];
    __shared__ float red2[4];
    const int row = blockIdx.x;
    const int tid = threadIdx.x;
    const size_t base = (size_t)row * D_;

    float v0 = a[base + tid];
    float v1 = a[base + tid + 256];
    float v2 = a[base + tid + 512];
    float s = v0 + v1 + v2;
#pragma unroll
    for (int o = 32; o > 0; o >>= 1) s += __shfl_xor(s, o, 64);
    if ((tid & 63) == 0) red[tid >> 6] = s;
    __syncthreads();
    float mean = (red[0] + red[1] + red[2] + red[3]) * (1.0f / 768.0f);
    float d0 = v0 - mean, d1 = v1 - mean, d2 = v2 - mean;
    float sq = d0 * d0 + d1 * d1 + d2 * d2;
#pragma unroll
    for (int o = 32; o > 0; o >>= 1) sq += __shfl_xor(sq, o, 64);
    if ((tid & 63) == 0) red2[tid >> 6] = sq;
    __syncthreads();
    float var = (red2[0] + red2[1] + red2[2] + red2[3]) * (1.0f / 768.0f);
    float inv = rsqrtf(var + 1e-6f);
    lnb[base + tid]       = d0 * inv * osc[tid]       + ob[tid];
    lnb[base + tid + 256] = d1 * inv * osc[tid + 256] + ob[tid + 256];
    lnb[base + tid + 512] = d2 * inv * osc[tid + 512] + ob[tid + 512];
}

// ---------------------------------------------------------------------------
// Kernel 5: out = ln_buf @ W_out + b_out, fp32 output.
// ---------------------------------------------------------------------------
__global__ __launch_bounds__(256) void gemm_out(const float* __restrict__ a,
                                                const float* __restrict__ w,
                                                const float* __restrict__ bias,
                                                float* __restrict__ out) {
    __shared__ float As[64][17];
    __shared__ float Bs[16][64];
    const int tid = threadIdx.x;
    const int tx = tid & 15, ty = tid >> 4;
    const int rowBase = blockIdx.y * 64;
    const int colBase = blockIdx.x * 64;
    float acc[4][4] = {};

    for (int k0 = 0; k0 < D_; k0 += 16) {
#pragma unroll
        for (int i = 0; i < 4; i++) {
            int e  = tid + i * 256;
            int ar = e >> 4, ac = e & 15;
            As[ar][ac] = a[(size_t)(rowBase + ar) * D_ + k0 + ac];
            int br = e >> 6, bc = e & 63;
            Bs[br][bc] = w[(size_t)(k0 + br) * D_ + colBase + bc];
        }
        __syncthreads();
#pragma unroll
        for (int kk = 0; kk < 16; kk++) {
            float a0 = As[ty * 4 + 0][kk];
            float a1 = As[ty * 4 + 1][kk];
            float a2 = As[ty * 4 + 2][kk];
            float a3 = As[ty * 4 + 3][kk];
            float4 bv = *(const float4*)&Bs[kk][tx * 4];
            acc[0][0] += a0 * bv.x; acc[0][1] += a0 * bv.y; acc[0][2] += a0 * bv.z; acc[0][3] += a0 * bv.w;
            acc[1][0] += a1 * bv.x; acc[1][1] += a1 * bv.y; acc[1][2] += a1 * bv.z; acc[1][3] += a1 * bv.w;
            acc[2][0] += a2 * bv.x; acc[2][1] += a2 * bv.y; acc[2][2] += a2 * bv.z; acc[2][3] += a2 * bv.w;
            acc[3][0] += a3 * bv.x; acc[3][1] += a3 * bv.y; acc[3][2] += a3 * bv.z; acc[3][3] += a3 * bv.w;
        }
        __syncthreads();
    }

#pragma unroll
    for (int i = 0; i < 4; i++) {
        int r = rowBase + ty * 4 + i;
#pragma unroll
        for (int j = 0; j < 4; j++) {
            int c = colBase + tx * 4 + j;
            out[(size_t)r * D_ + c] = acc[i][j] + bias[c];
        }
    }
}

// ---------------------------------------------------------------------------
extern "C" void kernel_launch(void* const* d_in, const int* in_sizes, int n_in,
                              void* d_out, int out_size, void* d_ws, size_t ws_size,
                              hipStream_t stream) {
    const float* x    = (const float*)d_in[0];
    const float* Wqkv = (const float*)d_in[1];
    const float* qs   = (const float*)d_in[2];
    const float* qb   = (const float*)d_in[3];
    const float* ks   = (const float*)d_in[4];
    const float* kb   = (const float*)d_in[5];
    const float* osc  = (const float*)d_in[6];
    const float* ob   = (const float*)d_in[7];
    const float* Wout = (const float*)d_in[8];
    const float* bout = (const float*)d_in[9];
    float* out = (float*)d_out;

    // Workspace (37.75 MB): qkv [3][B][H][P][hd] fp32.
    // d_out doubles as the fp32 attention-output scratch (fully rewritten by
    // gemm_out at the end). ln_buf overlays the q-region (dead after attn).
    float* qkv    = (float*)d_ws;
    float* attn_s = out;
    float* ln_buf = qkv;   // first B*H*P*64 floats = exactly B*P*D

    gemm_qkv<<<dim3(N1_ / 64, M_ / 64), 256, 0, stream>>>(x, Wqkv, qkv);
    ln_qk<<<dim3((2 * B_ * H_ * P_) / 4), 256, 0, stream>>>(qkv, qs, qb, ks, kb);
    attn<<<dim3(P_ / 4, B_ * H_), 256, 0, stream>>>(qkv, attn_s);
    ln_o<<<dim3(M_), 256, 0, stream>>>(attn_s, ln_buf, osc, ob);
    gemm_out<<<dim3(D_ / 64, M_ / 64), 256, 0, stream>>>(ln_buf, Wout, bout, out);
}

// Round 4
// 554.781 us; speedup vs baseline: 18.4936x; 18.4936x over previous
//
#include <hip/hip_runtime.h>
#include <hip/hip_bf16.h>

// Problem constants (B=2, P=2048, D=768, H=12, hd=64)
#define B_  2
#define P_  2048
#define D_  768
#define H_  12
#define HD_ 64
#define M_  (B_ * P_)   // 4096
#define N1_ (3 * D_)    // 2304

typedef __attribute__((ext_vector_type(8))) short short8;   // 8 bf16 (4 VGPRs)
typedef __attribute__((ext_vector_type(4))) float f32x4;    // MFMA accumulator

__device__ __forceinline__ unsigned short f2bf(float f) {
    unsigned u = __float_as_uint(f);
    u += 0x7fffu + ((u >> 16) & 1u);   // RNE
    return (unsigned short)(u >> 16);
}

// ---------------------------------------------------------------------------
// Kernel 1: qkv = x @ W_qkv, scattered into [3][B][H][P][hd] fp32 layout.
// Tiled 64x64, BK=16, 256 threads (16x16), 4x4 per thread.  (unchanged)
// ---------------------------------------------------------------------------
__global__ __launch_bounds__(256) void gemm_qkv(const float* __restrict__ x,
                                                const float* __restrict__ w,
                                                float* __restrict__ qkv) {
    __shared__ float As[64][17];
    __shared__ float Bs[16][64];
    const int tid = threadIdx.x;
    const int tx = tid & 15, ty = tid >> 4;
    const int rowBase = blockIdx.y * 64;
    const int colBase = blockIdx.x * 64;
    float acc[4][4] = {};

    for (int k0 = 0; k0 < D_; k0 += 16) {
#pragma unroll
        for (int i = 0; i < 4; i++) {
            int e  = tid + i * 256;
            int ar = e >> 4, ac = e & 15;
            As[ar][ac] = x[(size_t)(rowBase + ar) * D_ + k0 + ac];
            int br = e >> 6, bc = e & 63;
            Bs[br][bc] = w[(size_t)(k0 + br) * N1_ + colBase + bc];
        }
        __syncthreads();
#pragma unroll
        for (int kk = 0; kk < 16; kk++) {
            float a0 = As[ty * 4 + 0][kk];
            float a1 = As[ty * 4 + 1][kk];
            float a2 = As[ty * 4 + 2][kk];
            float a3 = As[ty * 4 + 3][kk];
            float4 bv = *(const float4*)&Bs[kk][tx * 4];
            acc[0][0] += a0 * bv.x; acc[0][1] += a0 * bv.y; acc[0][2] += a0 * bv.z; acc[0][3] += a0 * bv.w;
            acc[1][0] += a1 * bv.x; acc[1][1] += a1 * bv.y; acc[1][2] += a1 * bv.z; acc[1][3] += a1 * bv.w;
            acc[2][0] += a2 * bv.x; acc[2][1] += a2 * bv.y; acc[2][2] += a2 * bv.z; acc[2][3] += a2 * bv.w;
            acc[3][0] += a3 * bv.x; acc[3][1] += a3 * bv.y; acc[3][2] += a3 * bv.z; acc[3][3] += a3 * bv.w;
        }
        __syncthreads();
    }

#pragma unroll
    for (int i = 0; i < 4; i++) {
        int r  = rowBase + ty * 4 + i;
        int bb = r >> 11;
        int p  = r & 2047;
#pragma unroll
        for (int j = 0; j < 4; j++) {
            int c    = colBase + tx * 4 + j;
            int comp = c / D_;
            int rem  = c - comp * D_;
            int h    = rem >> 6;
            int d    = rem & 63;
            size_t addr = ((((size_t)comp * B_ + bb) * H_ + h) * P_ + p) * HD_ + d;
            qkv[addr] = acc[i][j];
        }
    }
}

// ---------------------------------------------------------------------------
// Kernel 2: per-head LayerNorm over hd=64 for q and k rows, in place.
// q rows also get * hd^-0.5 = 0.125.  (unchanged)
// ---------------------------------------------------------------------------
__global__ __launch_bounds__(256) void ln_qk(float* __restrict__ qkv,
                                             const float* __restrict__ qs, const float* __restrict__ qb,
                                             const float* __restrict__ ks, const float* __restrict__ kb) {
    const int wid  = threadIdx.x >> 6;
    const int lane = threadIdx.x & 63;
    const int row  = blockIdx.x * 4 + wid;
    const bool is_q = row < B_ * H_ * P_;
    const size_t base = (size_t)row * HD_;

    float v = qkv[base + lane];
    float s = v;
#pragma unroll
    for (int o = 32; o > 0; o >>= 1) s += __shfl_xor(s, o, 64);
    float mean = s * (1.0f / 64.0f);
    float d  = v - mean;
    float sq = d * d;
#pragma unroll
    for (int o = 32; o > 0; o >>= 1) sq += __shfl_xor(sq, o, 64);
    float inv = rsqrtf(sq * (1.0f / 64.0f) + 1e-6f);
    float sc  = is_q ? qs[lane] : ks[lane];
    float bi  = is_q ? qb[lane] : kb[lane];
    float r   = d * inv * sc + bi;
    if (is_q) r *= 0.125f;
    qkv[base + lane] = r;
}

// ---------------------------------------------------------------------------
// Kernel 3: flash attention, bf16 MFMA 16x16x32.
// Block = one (b,h) x 64 q rows. 4 waves; wave w owns q rows w*16..+15.
// K-tiles of 64 keys staged fp32->bf16 in LDS (coalesced); V staged transposed.
// Online softmax fp32; P->LDS roundtrip (C-layout -> A-layout); O accum fp32.
// MFMA layouts (verified, learn_hip m89/m120): A[m=lane&15][k=quad*8+j],
// B[k=quad*8+j][n=lane&15], C/D[row=quad*4+reg][col=lane&15].
// ---------------------------------------------------------------------------
__global__ __launch_bounds__(256) void attn_mfma(const float* __restrict__ qkv,
                                                 float* __restrict__ attn_s) {
    const int p0 = blockIdx.x * 64;
    const int bh = blockIdx.y;            // 0..23
    const int b  = bh / H_, h = bh % H_;
    const int tid  = threadIdx.x;
    const int lane = tid & 63;
    const int wv   = tid >> 6;            // wave 0..3
    const int quad = lane >> 4;           // 0..3
    const int col  = lane & 15;

    __shared__ __align__(16) unsigned short Qs[64][72];      // [q][dim]
    __shared__ __align__(16) unsigned short Ks[64][72];      // [key][dim]
    __shared__ __align__(16) unsigned short Vs[64][72];      // [dim][key] (transposed)
    __shared__ __align__(16) unsigned short Ps[4][16][72];   // per-wave [q][key]

    const size_t hs = (size_t)P_ * HD_;
    const float* qg = qkv + ((size_t)(0 * B_ + b) * H_ + h) * hs + (size_t)p0 * HD_;
    const float* kg = qkv + ((size_t)(1 * B_ + b) * H_ + h) * hs;
    const float* vg = qkv + ((size_t)(2 * B_ + b) * H_ + h) * hs;

    // Stage Q tile (64 rows x 64 dims), fp32 -> bf16
#pragma unroll
    for (int i = 0; i < 4; i++) {
        int e = tid + i * 256;             // 0..1023 float4 index
        int r = e >> 4, c4 = e & 15;
        float4 v = *(const float4*)(qg + (size_t)r * HD_ + c4 * 4);
        unsigned short* dst = &Qs[r][c4 * 4];
        dst[0] = f2bf(v.x); dst[1] = f2bf(v.y); dst[2] = f2bf(v.z); dst[3] = f2bf(v.w);
    }

    // Q fragments (invariant across k-tiles): A[m=col][k=kstep*32+quad*8+j]
    __syncthreads();
    short8 aq0 = *(const short8*)&Qs[wv * 16 + col][0 * 32 + quad * 8];
    short8 aq1 = *(const short8*)&Qs[wv * 16 + col][1 * 32 + quad * 8];

    // Online-softmax state: rows quad*4+r (replicated across the 16 cols)
    float m_i[4] = {-1e30f, -1e30f, -1e30f, -1e30f};
    float l_i[4] = {0.f, 0.f, 0.f, 0.f};
    f32x4 oacc[4];                          // [ntile] -> out dims nt*16+col, rows quad*4+reg
#pragma unroll
    for (int nt = 0; nt < 4; nt++) oacc[nt] = (f32x4){0.f, 0.f, 0.f, 0.f};

    for (int kt = 0; kt < P_ / 64; kt++) {
        __syncthreads();   // previous tile's reads of Ks/Vs complete
        const float* kg_t = kg + (size_t)kt * 64 * HD_;
        const float* vg_t = vg + (size_t)kt * 64 * HD_;
#pragma unroll
        for (int i = 0; i < 4; i++) {
            int e = tid + i * 256;
            int r = e >> 4, c4 = e & 15;
            float4 kv = *(const float4*)(kg_t + (size_t)r * HD_ + c4 * 4);
            unsigned short* dst = &Ks[r][c4 * 4];
            dst[0] = f2bf(kv.x); dst[1] = f2bf(kv.y); dst[2] = f2bf(kv.z); dst[3] = f2bf(kv.w);
            float4 vv = *(const float4*)(vg_t + (size_t)r * HD_ + c4 * 4);
            Vs[c4 * 4 + 0][r] = f2bf(vv.x);
            Vs[c4 * 4 + 1][r] = f2bf(vv.y);
            Vs[c4 * 4 + 2][r] = f2bf(vv.z);
            Vs[c4 * 4 + 3][r] = f2bf(vv.w);
        }
        __syncthreads();

        // S = Q(16x64) @ K-tile^T(64x64): 4 n-tiles x 2 k-steps
        f32x4 s[4];
#pragma unroll
        for (int nt = 0; nt < 4; nt++) {
            s[nt] = (f32x4){0.f, 0.f, 0.f, 0.f};
            short8 b0 = *(const short8*)&Ks[nt * 16 + col][0 * 32 + quad * 8];
            short8 b1 = *(const short8*)&Ks[nt * 16 + col][1 * 32 + quad * 8];
            s[nt] = __builtin_amdgcn_mfma_f32_16x16x32_bf16(aq0, b0, s[nt], 0, 0, 0);
            s[nt] = __builtin_amdgcn_mfma_f32_16x16x32_bf16(aq1, b1, s[nt], 0, 0, 0);
        }

        // Online softmax per row r (row = quad*4+r)
#pragma unroll
        for (int r = 0; r < 4; r++) {
            float mt = fmaxf(fmaxf(s[0][r], s[1][r]), fmaxf(s[2][r], s[3][r]));
#pragma unroll
            for (int off = 1; off < 16; off <<= 1) mt = fmaxf(mt, __shfl_xor(mt, off, 64));
            float mnew = fmaxf(m_i[r], mt);
            float alpha = __expf(m_i[r] - mnew);
            float rs = 0.f;
#pragma unroll
            for (int nt = 0; nt < 4; nt++) {
                float p = __expf(s[nt][r] - mnew);
                rs += p;
                Ps[wv][quad * 4 + r][nt * 16 + col] = f2bf(p);
            }
#pragma unroll
            for (int off = 1; off < 16; off <<= 1) rs += __shfl_xor(rs, off, 64);
            l_i[r] = l_i[r] * alpha + rs;
            m_i[r] = mnew;
#pragma unroll
            for (int nt = 0; nt < 4; nt++) oacc[nt][r] *= alpha;
        }
        __syncthreads();   // Ps visible (and lane-exchange safety)

        // O += P(16x64) @ V-tile(64x64)
#pragma unroll
        for (int nt = 0; nt < 4; nt++) {
#pragma unroll
            for (int ks2 = 0; ks2 < 2; ks2++) {
                short8 a = *(const short8*)&Ps[wv][col][ks2 * 32 + quad * 8];
                short8 bfr = *(const short8*)&Vs[nt * 16 + col][ks2 * 32 + quad * 8];
                oacc[nt] = __builtin_amdgcn_mfma_f32_16x16x32_bf16(a, bfr, oacc[nt], 0, 0, 0);
            }
        }
    }

    // Writeback: row = quad*4+r (q), col within n-tile = out dim
#pragma unroll
    for (int r = 0; r < 4; r++) {
        float invl = 1.0f / l_i[r];
        int q = p0 + wv * 16 + quad * 4 + r;
        float* dst = attn_s + (size_t)(b * P_ + q) * D_ + h * HD_;
#pragma unroll
        for (int nt = 0; nt < 4; nt++) dst[nt * 16 + col] = oacc[nt][r] * invl;
    }
}

// ---------------------------------------------------------------------------
// Kernel 4: LayerNorm over D=768. Reads d_out scratch, writes ln_buf.
// ---------------------------------------------------------------------------
__global__ __launch_bounds__(256) void ln_o(const float* __restrict__ a,
                                            float* __restrict__ lnb,
                                            const float* __restrict__ osc,
                                            const float* __restrict__ ob) {
    __shared__ float red[4];
    __shared__ float red2[4];
    const int row = blockIdx.x;
    const int tid = threadIdx.x;
    const size_t base = (size_t)row * D_;

    float v0 = a[base + tid];
    float v1 = a[base + tid + 256];
    float v2 = a[base + tid + 512];
    float s = v0 + v1 + v2;
#pragma unroll
    for (int o = 32; o > 0; o >>= 1) s += __shfl_xor(s, o, 64);
    if ((tid & 63) == 0) red[tid >> 6] = s;
    __syncthreads();
    float mean = (red[0] + red[1] + red[2] + red[3]) * (1.0f / 768.0f);
    float d0 = v0 - mean, d1 = v1 - mean, d2 = v2 - mean;
    float sq = d0 * d0 + d1 * d1 + d2 * d2;
#pragma unroll
    for (int o = 32; o > 0; o >>= 1) sq += __shfl_xor(sq, o, 64);
    if ((tid & 63) == 0) red2[tid >> 6] = sq;
    __syncthreads();
    float var = (red2[0] + red2[1] + red2[2] + red2[3]) * (1.0f / 768.0f);
    float inv = rsqrtf(var + 1e-6f);
    lnb[base + tid]       = d0 * inv * osc[tid]       + ob[tid];
    lnb[base + tid + 256] = d1 * inv * osc[tid + 256] + ob[tid + 256];
    lnb[base + tid + 512] = d2 * inv * osc[tid + 512] + ob[tid + 512];
}

// ---------------------------------------------------------------------------
// Kernel 5: out = ln_buf @ W_out + b_out, fp32 output.  (unchanged)
// ---------------------------------------------------------------------------
__global__ __launch_bounds__(256) void gemm_out(const float* __restrict__ a,
                                                const float* __restrict__ w,
                                                const float* __restrict__ bias,
                                                float* __restrict__ out) {
    __shared__ float As[64][17];
    __shared__ float Bs[16][64];
    const int tid = threadIdx.x;
    const int tx = tid & 15, ty = tid >> 4;
    const int rowBase = blockIdx.y * 64;
    const int colBase = blockIdx.x * 64;
    float acc[4][4] = {};

    for (int k0 = 0; k0 < D_; k0 += 16) {
#pragma unroll
        for (int i = 0; i < 4; i++) {
            int e  = tid + i * 256;
            int ar = e >> 4, ac = e & 15;
            As[ar][ac] = a[(size_t)(rowBase + ar) * D_ + k0 + ac];
            int br = e >> 6, bc = e & 63;
            Bs[br][bc] = w[(size_t)(k0 + br) * D_ + colBase + bc];
        }
        __syncthreads();
#pragma unroll
        for (int kk = 0; kk < 16; kk++) {
            float a0 = As[ty * 4 + 0][kk];
            float a1 = As[ty * 4 + 1][kk];
            float a2 = As[ty * 4 + 2][kk];
            float a3 = As[ty * 4 + 3][kk];
            float4 bv = *(const float4*)&Bs[kk][tx * 4];
            acc[0][0] += a0 * bv.x; acc[0][1] += a0 * bv.y; acc[0][2] += a0 * bv.z; acc[0][3] += a0 * bv.w;
            acc[1][0] += a1 * bv.x; acc[1][1] += a1 * bv.y; acc[1][2] += a1 * bv.z; acc[1][3] += a1 * bv.w;
            acc[2][0] += a2 * bv.x; acc[2][1] += a2 * bv.y; acc[2][2] += a2 * bv.z; acc[2][3] += a2 * bv.w;
            acc[3][0] += a3 * bv.x; acc[3][1] += a3 * bv.y; acc[3][2] += a3 * bv.z; acc[3][3] += a3 * bv.w;
        }
        __syncthreads();
    }

#pragma unroll
    for (int i = 0; i < 4; i++) {
        int r = rowBase + ty * 4 + i;
#pragma unroll
        for (int j = 0; j < 4; j++) {
            int c = colBase + tx * 4 + j;
            out[(size_t)r * D_ + c] = acc[i][j] + bias[c];
        }
    }
}

// ---------------------------------------------------------------------------
extern "C" void kernel_launch(void* const* d_in, const int* in_sizes, int n_in,
                              void* d_out, int out_size, void* d_ws, size_t ws_size,
                              hipStream_t stream) {
    const float* x    = (const float*)d_in[0];
    const float* Wqkv = (const float*)d_in[1];
    const float* qs   = (const float*)d_in[2];
    const float* qb   = (const float*)d_in[3];
    const float* ks   = (const float*)d_in[4];
    const float* kb   = (const float*)d_in[5];
    const float* osc  = (const float*)d_in[6];
    const float* ob   = (const float*)d_in[7];
    const float* Wout = (const float*)d_in[8];
    const float* bout = (const float*)d_in[9];
    float* out = (float*)d_out;

    float* qkv    = (float*)d_ws;   // [3][B][H][P][hd] fp32, 37.75 MB
    float* attn_s = out;            // d_out doubles as attention-output scratch
    float* ln_buf = qkv;            // overlays dead q-region after attn

    gemm_qkv<<<dim3(N1_ / 64, M_ / 64), 256, 0, stream>>>(x, Wqkv, qkv);
    ln_qk<<<dim3((2 * B_ * H_ * P_) / 4), 256, 0, stream>>>(qkv, qs, qb, ks, kb);
    attn_mfma<<<dim3(P_ / 64, B_ * H_), 256, 0, stream>>>(qkv, attn_s);
    ln_o<<<dim3(M_), 256, 0, stream>>>(attn_s, ln_buf, osc, ob);
    gemm_out<<<dim3(D_ / 64, M_ / 64), 256, 0, stream>>>(ln_buf, Wout, bout, out);
}

// Round 5
// 279.912 us; speedup vs baseline: 36.6541x; 1.9820x over previous
//
#include <hip/hip_runtime.h>
#include <hip/hip_bf16.h>

// Problem constants (B=2, P=2048, D=768, H=12, hd=64)
#define B_  2
#define P_  2048
#define D_  768
#define H_  12
#define HD_ 64
#define M_  (B_ * P_)   // 4096
#define N1_ (3 * D_)    // 2304

typedef __attribute__((ext_vector_type(8))) short short8;   // 8 bf16 (4 VGPRs)
typedef __attribute__((ext_vector_type(4))) float f32x4;    // MFMA accumulator
typedef unsigned short ushort;

__device__ __forceinline__ ushort f2bf(float f) {
    unsigned u = __float_as_uint(f);
    u += 0x7fffu + ((u >> 16) & 1u);   // RNE
    return (ushort)(u >> 16);
}

// ===========================================================================
// Kernel 1: qkv = x @ W_qkv (bf16 MFMA), fused per-head QK-LayerNorm epilogue,
// bf16 output scattered into [3][B][H][P][hd].
// 128x128 tile, BK=32, 4 waves (2x2), each wave 64x64 via 4x4 16x16x32 MFMAs.
// A staged [m][k] (coalesced float4 + cvt); B staged transposed [n][k] via
// coalesced scalar loads + packed ds_write_b128.
// MFMA layouts (verified): A[m=lane&15][k=quad*8+j], B[k=quad*8+j][n=lane&15],
// C/D[row=quad*4+reg][col=lane&15].
// ===========================================================================
__global__ __launch_bounds__(256) void gemm_qkv_mfma(
        const float* __restrict__ x, const float* __restrict__ w,
        const float* __restrict__ qs, const float* __restrict__ qb,
        const float* __restrict__ ks, const float* __restrict__ kb,
        ushort* __restrict__ qkv) {
    __shared__ __align__(16) ushort As[128][40];   // [m][k], pad to 40
    __shared__ __align__(16) ushort Bs[128][40];   // [n][k], pad to 40

    const int tid  = threadIdx.x;
    const int lane = tid & 63;
    const int wv   = tid >> 6;
    const int quad = lane >> 4;
    const int col  = lane & 15;
    const int wr   = (wv >> 1) * 64;   // wave m-offset in tile
    const int wc   = (wv & 1) * 64;    // wave n-offset in tile
    const int rowBase = blockIdx.y * 128;
    const int colBase = blockIdx.x * 128;

    const int nB    = tid & 127;       // B staging: this thread's n
    const int khalf = tid >> 7;        // 0/1 -> k 0..15 / 16..31

    f32x4 acc[4][4];
#pragma unroll
    for (int i = 0; i < 4; i++)
#pragma unroll
        for (int j = 0; j < 4; j++) acc[i][j] = (f32x4){0.f, 0.f, 0.f, 0.f};

    for (int kt = 0; kt < D_ / 32; kt++) {
        const int k0 = kt * 32;
        // --- stage A: 128 x 32 fp32 -> bf16 ---
#pragma unroll
        for (int i = 0; i < 4; i++) {
            int e = tid + i * 256;           // float4 index over 1024
            int m = e >> 3, c4 = e & 7;
            float4 v = *(const float4*)(x + (size_t)(rowBase + m) * D_ + k0 + c4 * 4);
            ushort u4[4] = {f2bf(v.x), f2bf(v.y), f2bf(v.z), f2bf(v.w)};
            *(uint2*)&As[m][c4 * 4] = *(uint2*)u4;
        }
        // --- stage B transposed: 16 coalesced scalar loads -> 2 b128 writes ---
        {
            float bv[16];
#pragma unroll
            for (int j = 0; j < 16; j++)
                bv[j] = w[(size_t)(k0 + khalf * 16 + j) * N1_ + colBase + nB];
            ushort us[16];
#pragma unroll
            for (int j = 0; j < 16; j++) us[j] = f2bf(bv[j]);
            *(short8*)&Bs[nB][khalf * 16]     = *(short8*)&us[0];
            *(short8*)&Bs[nB][khalf * 16 + 8] = *(short8*)&us[8];
        }
        __syncthreads();
        // --- compute ---
        short8 af[4], bf[4];
#pragma unroll
        for (int mt = 0; mt < 4; mt++) af[mt] = *(const short8*)&As[wr + mt * 16 + col][quad * 8];
#pragma unroll
        for (int nt = 0; nt < 4; nt++) bf[nt] = *(const short8*)&Bs[wc + nt * 16 + col][quad * 8];
#pragma unroll
        for (int mt = 0; mt < 4; mt++)
#pragma unroll
            for (int nt = 0; nt < 4; nt++)
                acc[mt][nt] = __builtin_amdgcn_mfma_f32_16x16x32_bf16(af[mt], bf[nt], acc[mt][nt], 0, 0, 0);
        __syncthreads();
    }

    // --- epilogue: wave's 64 cols = exactly one (comp, head). Fuse LN for q/k.
    const int comp = colBase / D_;                       // block-uniform (768 % 128-tile aligned)
    const int rem  = colBase + wc - comp * D_;
    const int h    = rem >> 6;
    float sc4[4] = {0, 0, 0, 0}, bi4[4] = {0, 0, 0, 0};
    if (comp == 0) {
#pragma unroll
        for (int nt = 0; nt < 4; nt++) { sc4[nt] = qs[nt * 16 + col]; bi4[nt] = qb[nt * 16 + col]; }
    } else if (comp == 1) {
#pragma unroll
        for (int nt = 0; nt < 4; nt++) { sc4[nt] = ks[nt * 16 + col]; bi4[nt] = kb[nt * 16 + col]; }
    }

#pragma unroll
    for (int mt = 0; mt < 4; mt++) {
#pragma unroll
        for (int r = 0; r < 4; r++) {
            int m  = rowBase + wr + mt * 16 + quad * 4 + r;
            int bb = m >> 11;
            int p  = m & 2047;
            float v0 = acc[mt][0][r], v1 = acc[mt][1][r], v2 = acc[mt][2][r], v3 = acc[mt][3][r];
            if (comp < 2) {
                float s = v0 + v1 + v2 + v3;
#pragma unroll
                for (int off = 1; off < 16; off <<= 1) s += __shfl_xor(s, off, 64);
                float mean = s * (1.0f / 64.0f);
                float d0 = v0 - mean, d1 = v1 - mean, d2 = v2 - mean, d3 = v3 - mean;
                float sq = d0 * d0 + d1 * d1 + d2 * d2 + d3 * d3;
#pragma unroll
                for (int off = 1; off < 16; off <<= 1) sq += __shfl_xor(sq, off, 64);
                float inv = rsqrtf(sq * (1.0f / 64.0f) + 1e-6f);
                v0 = d0 * inv * sc4[0] + bi4[0];
                v1 = d1 * inv * sc4[1] + bi4[1];
                v2 = d2 * inv * sc4[2] + bi4[2];
                v3 = d3 * inv * sc4[3] + bi4[3];
                if (comp == 0) { v0 *= 0.125f; v1 *= 0.125f; v2 *= 0.125f; v3 *= 0.125f; }
            }
            size_t base = ((((size_t)comp * B_ + bb) * H_ + h) * P_ + p) * HD_;
            qkv[base +  0 + col] = f2bf(v0);
            qkv[base + 16 + col] = f2bf(v1);
            qkv[base + 32 + col] = f2bf(v2);
            qkv[base + 48 + col] = f2bf(v3);
        }
    }
}

// ===========================================================================
// Kernel 2: flash attention, bf16 MFMA 16x16x32, bf16 qkv input.
// Block = one (b,h) x 64 q rows. 4 waves; wave w owns q rows w*16..+15.
// ===========================================================================
__global__ __launch_bounds__(256) void attn_mfma(const ushort* __restrict__ qkv,
                                                 float* __restrict__ attn_s) {
    const int p0 = blockIdx.x * 64;
    const int bh = blockIdx.y;
    const int b  = bh / H_, h = bh % H_;
    const int tid  = threadIdx.x;
    const int lane = tid & 63;
    const int wv   = tid >> 6;
    const int quad = lane >> 4;
    const int col  = lane & 15;

    __shared__ __align__(16) ushort Qs[64][72];
    __shared__ __align__(16) ushort Ks[64][72];
    __shared__ __align__(16) ushort Vs[64][72];      // [dim][key] transposed
    __shared__ __align__(16) ushort Ps[4][16][72];

    const size_t hs = (size_t)P_ * HD_;
    const ushort* qg = qkv + ((size_t)(0 * B_ + b) * H_ + h) * hs + (size_t)p0 * HD_;
    const ushort* kg = qkv + ((size_t)(1 * B_ + b) * H_ + h) * hs;
    const ushort* vg = qkv + ((size_t)(2 * B_ + b) * H_ + h) * hs;

    // Stage Q (64x64 bf16): 2 x uint4 per thread, direct copy
#pragma unroll
    for (int i = 0; i < 2; i++) {
        int e = tid + i * 256;           // uint4 index over 512
        int r = e >> 3, c8 = e & 7;
        *(uint4*)&Qs[r][c8 * 8] = *(const uint4*)(qg + (size_t)r * HD_ + c8 * 8);
    }
    __syncthreads();
    short8 aq0 = *(const short8*)&Qs[wv * 16 + col][0 * 32 + quad * 8];
    short8 aq1 = *(const short8*)&Qs[wv * 16 + col][1 * 32 + quad * 8];

    float m_i[4] = {-1e30f, -1e30f, -1e30f, -1e30f};
    float l_i[4] = {0.f, 0.f, 0.f, 0.f};
    f32x4 oacc[4];
#pragma unroll
    for (int nt = 0; nt < 4; nt++) oacc[nt] = (f32x4){0.f, 0.f, 0.f, 0.f};

    const int vd = tid & 63, vkh = tid >> 6;   // V staging mapping

    for (int kt = 0; kt < P_ / 64; kt++) {
        __syncthreads();
        const ushort* kg_t = kg + (size_t)kt * 64 * HD_;
        const ushort* vg_t = vg + (size_t)kt * 64 * HD_;
#pragma unroll
        for (int i = 0; i < 2; i++) {
            int e = tid + i * 256;
            int r = e >> 3, c8 = e & 7;
            *(uint4*)&Ks[r][c8 * 8] = *(const uint4*)(kg_t + (size_t)r * HD_ + c8 * 8);
        }
        // V transposed: 16 coalesced ushort loads -> 2 b128 writes
        {
            ushort us[16];
#pragma unroll
            for (int j = 0; j < 16; j++)
                us[j] = vg_t[(size_t)(vkh * 16 + j) * HD_ + vd];
            *(short8*)&Vs[vd][vkh * 16]     = *(short8*)&us[0];
            *(short8*)&Vs[vd][vkh * 16 + 8] = *(short8*)&us[8];
        }
        __syncthreads();

        // S = Q @ K^T
        f32x4 s[4];
#pragma unroll
        for (int nt = 0; nt < 4; nt++) {
            s[nt] = (f32x4){0.f, 0.f, 0.f, 0.f};
            short8 b0 = *(const short8*)&Ks[nt * 16 + col][0 * 32 + quad * 8];
            short8 b1 = *(const short8*)&Ks[nt * 16 + col][1 * 32 + quad * 8];
            s[nt] = __builtin_amdgcn_mfma_f32_16x16x32_bf16(aq0, b0, s[nt], 0, 0, 0);
            s[nt] = __builtin_amdgcn_mfma_f32_16x16x32_bf16(aq1, b1, s[nt], 0, 0, 0);
        }

        // Online softmax per row (row = quad*4+r)
#pragma unroll
        for (int r = 0; r < 4; r++) {
            float mt = fmaxf(fmaxf(s[0][r], s[1][r]), fmaxf(s[2][r], s[3][r]));
#pragma unroll
            for (int off = 1; off < 16; off <<= 1) mt = fmaxf(mt, __shfl_xor(mt, off, 64));
            float mnew = fmaxf(m_i[r], mt);
            float alpha = __expf(m_i[r] - mnew);
            float rs = 0.f;
#pragma unroll
            for (int nt = 0; nt < 4; nt++) {
                float p = __expf(s[nt][r] - mnew);
                rs += p;
                Ps[wv][quad * 4 + r][nt * 16 + col] = f2bf(p);
            }
#pragma unroll
            for (int off = 1; off < 16; off <<= 1) rs += __shfl_xor(rs, off, 64);
            l_i[r] = l_i[r] * alpha + rs;
            m_i[r] = mnew;
#pragma unroll
            for (int nt = 0; nt < 4; nt++) oacc[nt][r] *= alpha;
        }
        __syncthreads();

        // O += P @ V
#pragma unroll
        for (int nt = 0; nt < 4; nt++) {
#pragma unroll
            for (int ks2 = 0; ks2 < 2; ks2++) {
                short8 a   = *(const short8*)&Ps[wv][col][ks2 * 32 + quad * 8];
                short8 bfr = *(const short8*)&Vs[nt * 16 + col][ks2 * 32 + quad * 8];
                oacc[nt] = __builtin_amdgcn_mfma_f32_16x16x32_bf16(a, bfr, oacc[nt], 0, 0, 0);
            }
        }
    }

#pragma unroll
    for (int r = 0; r < 4; r++) {
        float invl = 1.0f / l_i[r];
        int q = p0 + wv * 16 + quad * 4 + r;
        float* dst = attn_s + (size_t)(b * P_ + q) * D_ + h * HD_;
#pragma unroll
        for (int nt = 0; nt < 4; nt++) dst[nt * 16 + col] = oacc[nt][r] * invl;
    }
}

// ===========================================================================
// Kernel 3: LayerNorm over D=768. fp32 in (d_out scratch), bf16 out (ln_buf).
// ===========================================================================
__global__ __launch_bounds__(256) void ln_o(const float* __restrict__ a,
                                            ushort* __restrict__ lnb,
                                            const float* __restrict__ osc,
                                            const float* __restrict__ ob) {
    __shared__ float red[4];
    __shared__ float red2[4];
    const int row = blockIdx.x;
    const int tid = threadIdx.x;
    const size_t base = (size_t)row * D_;

    float v0 = a[base + tid];
    float v1 = a[base + tid + 256];
    float v2 = a[base + tid + 512];
    float s = v0 + v1 + v2;
#pragma unroll
    for (int o = 32; o > 0; o >>= 1) s += __shfl_xor(s, o, 64);
    if ((tid & 63) == 0) red[tid >> 6] = s;
    __syncthreads();
    float mean = (red[0] + red[1] + red[2] + red[3]) * (1.0f / 768.0f);
    float d0 = v0 - mean, d1 = v1 - mean, d2 = v2 - mean;
    float sq = d0 * d0 + d1 * d1 + d2 * d2;
#pragma unroll
    for (int o = 32; o > 0; o >>= 1) sq += __shfl_xor(sq, o, 64);
    if ((tid & 63) == 0) red2[tid >> 6] = sq;
    __syncthreads();
    float var = (red2[0] + red2[1] + red2[2] + red2[3]) * (1.0f / 768.0f);
    float inv = rsqrtf(var + 1e-6f);
    lnb[base + tid]       = f2bf(d0 * inv * osc[tid]       + ob[tid]);
    lnb[base + tid + 256] = f2bf(d1 * inv * osc[tid + 256] + ob[tid + 256]);
    lnb[base + tid + 512] = f2bf(d2 * inv * osc[tid + 512] + ob[tid + 512]);
}

// ===========================================================================
// Kernel 4: out = ln_buf(bf16) @ W_out(fp32->bf16) + b_out, fp32 output.
// Same MFMA structure as gemm_qkv_mfma.
// ===========================================================================
__global__ __launch_bounds__(256) void gemm_out_mfma(
        const ushort* __restrict__ a, const float* __restrict__ w,
        const float* __restrict__ bias, float* __restrict__ out) {
    __shared__ __align__(16) ushort As[128][40];
    __shared__ __align__(16) ushort Bs[128][40];

    const int tid  = threadIdx.x;
    const int lane = tid & 63;
    const int wv   = tid >> 6;
    const int quad = lane >> 4;
    const int col  = lane & 15;
    const int wr   = (wv >> 1) * 64;
    const int wc   = (wv & 1) * 64;
    const int rowBase = blockIdx.y * 128;
    const int colBase = blockIdx.x * 128;

    const int nB    = tid & 127;
    const int khalf = tid >> 7;

    f32x4 acc[4][4];
#pragma unroll
    for (int i = 0; i < 4; i++)
#pragma unroll
        for (int j = 0; j < 4; j++) acc[i][j] = (f32x4){0.f, 0.f, 0.f, 0.f};

    for (int kt = 0; kt < D_ / 32; kt++) {
        const int k0 = kt * 32;
        // stage A: direct bf16 copy, 2 x uint4 per thread
#pragma unroll
        for (int i = 0; i < 2; i++) {
            int e = tid + i * 256;           // uint4 index over 512
            int m = e >> 2, c8 = e & 3;
            *(uint4*)&As[m][c8 * 8] = *(const uint4*)(a + (size_t)(rowBase + m) * D_ + k0 + c8 * 8);
        }
        // stage B transposed
        {
            float bv[16];
#pragma unroll
            for (int j = 0; j < 16; j++)
                bv[j] = w[(size_t)(k0 + khalf * 16 + j) * D_ + colBase + nB];
            ushort us[16];
#pragma unroll
            for (int j = 0; j < 16; j++) us[j] = f2bf(bv[j]);
            *(short8*)&Bs[nB][khalf * 16]     = *(short8*)&us[0];
            *(short8*)&Bs[nB][khalf * 16 + 8] = *(short8*)&us[8];
        }
        __syncthreads();
        short8 af[4], bf[4];
#pragma unroll
        for (int mt = 0; mt < 4; mt++) af[mt] = *(const short8*)&As[wr + mt * 16 + col][quad * 8];
#pragma unroll
        for (int nt = 0; nt < 4; nt++) bf[nt] = *(const short8*)&Bs[wc + nt * 16 + col][quad * 8];
#pragma unroll
        for (int mt = 0; mt < 4; mt++)
#pragma unroll
            for (int nt = 0; nt < 4; nt++)
                acc[mt][nt] = __builtin_amdgcn_mfma_f32_16x16x32_bf16(af[mt], bf[nt], acc[mt][nt], 0, 0, 0);
        __syncthreads();
    }

    float b4[4];
#pragma unroll
    for (int nt = 0; nt < 4; nt++) b4[nt] = bias[colBase + wc + nt * 16 + col];
#pragma unroll
    for (int mt = 0; mt < 4; mt++) {
#pragma unroll
        for (int r = 0; r < 4; r++) {
            int m = rowBase + wr + mt * 16 + quad * 4 + r;
            float* dst = out + (size_t)m * D_ + colBase + wc;
#pragma unroll
            for (int nt = 0; nt < 4; nt++)
                dst[nt * 16 + col] = acc[mt][nt][r] + b4[nt];
        }
    }
}

// ---------------------------------------------------------------------------
extern "C" void kernel_launch(void* const* d_in, const int* in_sizes, int n_in,
                              void* d_out, int out_size, void* d_ws, size_t ws_size,
                              hipStream_t stream) {
    const float* x    = (const float*)d_in[0];
    const float* Wqkv = (const float*)d_in[1];
    const float* qs   = (const float*)d_in[2];
    const float* qb   = (const float*)d_in[3];
    const float* ks   = (const float*)d_in[4];
    const float* kb   = (const float*)d_in[5];
    const float* osc  = (const float*)d_in[6];
    const float* ob   = (const float*)d_in[7];
    const float* Wout = (const float*)d_in[8];
    const float* bout = (const float*)d_in[9];
    float* out = (float*)d_out;

    // Workspace: qkv [3][B][H][P][hd] bf16 = 18.9 MB.
    // d_out doubles as fp32 attention-output scratch (rewritten by gemm_out).
    // ln_buf (bf16, 6.3 MB) overlays the dead q-region of qkv after attn.
    ushort* qkv    = (ushort*)d_ws;
    float*  attn_s = out;
    ushort* ln_buf = qkv;

    gemm_qkv_mfma<<<dim3(N1_ / 128, M_ / 128), 256, 0, stream>>>(x, Wqkv, qs, qb, ks, kb, qkv);
    attn_mfma<<<dim3(P_ / 64, B_ * H_), 256, 0, stream>>>(qkv, attn_s);
    ln_o<<<dim3(M_), 256, 0, stream>>>(attn_s, ln_buf, osc, ob);
    gemm_out_mfma<<<dim3(D_ / 128, M_ / 128), 256, 0, stream>>>(ln_buf, Wout, bout, out);
}